// Round 2
// baseline (499.948 us; speedup 1.0000x reference)
//
#include <hip/hip_runtime.h>
#include <hip/hip_bf16.h>
#include <cstdint>

typedef __bf16 bf16;
typedef __attribute__((ext_vector_type(8))) __bf16 bf16x8;
typedef __attribute__((ext_vector_type(4))) __bf16 bf16x4;
typedef __attribute__((ext_vector_type(4))) float f32x4;

#define MFMA16 __builtin_amdgcn_mfma_f32_16x16x32_bf16
#define MASKV (-1e30f)

static constexpr int Lq  = 2048;
static constexpr int BQ  = 64;    // q rows per workgroup (16 per wave)
static constexpr int BKt = 128;   // keys per tile
static constexpr int TW  = 152;   // T strip stride (bf16 elems): 143 used + pad

__device__ __forceinline__ void async_load16(const void* g, void* l) {
  __builtin_amdgcn_global_load_lds(
      (__attribute__((address_space(1))) void*)g,
      (__attribute__((address_space(3))) void*)l, 16, 0, 0);
}

// ---------------------------------------------------------------------------
// fp32 -> bf16 conversion of all inputs
// ---------------------------------------------------------------------------
__global__ void convert_all(const float* __restrict__ q, const float* __restrict__ k,
                            const float* __restrict__ v, const float* __restrict__ wq,
                            const float* __restrict__ wk, const float* __restrict__ wv,
                            const float* __restrict__ fc, const float* __restrict__ E,
                            bf16* q_bf, bf16* k_bf, bf16* v_bf, bf16* wq_bf,
                            bf16* wk_bf, bf16* wv_bf, bf16* fc_bf, bf16* E_bf)
{
  int i = blockIdx.x * blockDim.x + threadIdx.x;   // vec4 index
  const float* src; bf16* dst; int rel;
  if      (i < 524288)  { src = q;  dst = q_bf;  rel = i; }
  else if (i < 1048576) { src = k;  dst = k_bf;  rel = i - 524288; }
  else if (i < 1572864) { src = v;  dst = v_bf;  rel = i - 1048576; }
  else if (i < 1638400) { src = wq; dst = wq_bf; rel = i - 1572864; }
  else if (i < 1703936) { src = wk; dst = wk_bf; rel = i - 1638400; }
  else if (i < 1769472) { src = wv; dst = wv_bf; rel = i - 1703936; }
  else if (i < 1835008) { src = fc; dst = fc_bf; rel = i - 1769472; }
  else if (i < 1867776) { src = E;  dst = E_bf;  rel = i - 1835008; }
  else return;
  float4 x = *(const float4*)(src + (size_t)rel * 4);
  bf16x4 o;
  o[0] = (bf16)x.x; o[1] = (bf16)x.y; o[2] = (bf16)x.z; o[3] = (bf16)x.w;
  *(bf16x4*)(dst + (size_t)rel * 4) = o;
}

// ---------------------------------------------------------------------------
// Generic 128x128-tile bf16 GEMM, C[i][j] = sum_k A[i][k]*B[j][k] + bias
// MODE 0: C bf16 (B,H,L,DH) ; MODE 2: C bf16 (B,H,DH,L), bias[i] ; MODE 3: fp32
// ---------------------------------------------------------------------------
template<int MODE>
__global__ __launch_bounds__(256, 2)
void gemm512(const bf16* __restrict__ A, const bf16* __restrict__ Bm,
             const float* __restrict__ bias, void* __restrict__ Cv)
{
  __shared__ __align__(16) char lA[16384];
  __shared__ __align__(16) char lB[16384];
  const int tid = threadIdx.x, lane = tid & 63, wv = tid >> 6;
  const int wr = wv >> 1, wc = wv & 1;
  const int tm = blockIdx.x, tn = blockIdx.y;

  f32x4 acc[4][4];
#pragma unroll
  for (int m = 0; m < 4; ++m)
#pragma unroll
    for (int n = 0; n < 4; ++n) acc[m][n] = (f32x4){0.f, 0.f, 0.f, 0.f};

  for (int k0 = 0; k0 < 512; k0 += 64) {
    __syncthreads();
#pragma unroll
    for (int it = 0; it < 4; ++it) {
      int slot = it * 256 + wv * 64 + lane;
      int row = slot >> 3, c = slot & 7;
      int gk = k0 + ((c ^ (row & 7)) * 8);
      async_load16(A  + (size_t)(tm * 128 + row) * 512 + gk, lA + (it * 256 + wv * 64) * 16);
      async_load16(Bm + (size_t)(tn * 128 + row) * 512 + gk, lB + (it * 256 + wv * 64) * 16);
    }
    __syncthreads();
#pragma unroll
    for (int kc = 0; kc < 2; ++kc) {
      bf16x8 af[4], bfr[4];
#pragma unroll
      for (int m = 0; m < 4; ++m) {
        int row = wr * 64 + m * 16 + (lane & 15);
        int ch = ((lane >> 4) + kc * 4) ^ (row & 7);
        af[m] = *(const bf16x8*)(lA + row * 128 + ch * 16);
      }
#pragma unroll
      for (int n = 0; n < 4; ++n) {
        int row = wc * 64 + n * 16 + (lane & 15);
        int ch = ((lane >> 4) + kc * 4) ^ (row & 7);
        bfr[n] = *(const bf16x8*)(lB + row * 128 + ch * 16);
      }
#pragma unroll
      for (int m = 0; m < 4; ++m)
#pragma unroll
        for (int n = 0; n < 4; ++n)
          acc[m][n] = MFMA16(af[m], bfr[n], acc[m][n], 0, 0, 0);
    }
  }

#pragma unroll
  for (int m = 0; m < 4; ++m)
#pragma unroll
    for (int n = 0; n < 4; ++n)
#pragma unroll
      for (int r = 0; r < 4; ++r) {
        int gi = tm * 128 + wr * 64 + m * 16 + 4 * (lane >> 4) + r;
        int gj = tn * 128 + wc * 64 + n * 16 + (lane & 15);
        float vv = acc[m][n][r] + ((MODE == 2) ? bias[gi] : bias[gj]);
        if (MODE == 3) {
          ((float*)Cv)[(size_t)gi * 512 + gj] = vv;
        } else if (MODE == 2) {
          int h = gi >> 6, dh = gi & 63, b = gj >> 11, l = gj & 2047;
          ((bf16*)Cv)[((size_t)((b * 8 + h) * 64 + dh)) * 2048 + l] = (bf16)vv;
        } else {
          int b = gi >> 11, l = gi & 2047, h = gj >> 6, dh = gj & 63;
          ((bf16*)Cv)[((size_t)((b * 8 + h) * 2048 + l)) * 64 + dh] = (bf16)vv;
        }
      }
}

// ---------------------------------------------------------------------------
// Logits for one 16(q-rows-of-this-wave) x 128(keys) tile, barrier-free.
// K fragments direct from global (L2-resident). T via per-wave bf16 strip.
// Output: acc_s = (QK + Srel)/8 with causal mask applied (MASKV).
// ---------------------------------------------------------------------------
__device__ __forceinline__ void attn_logits2(
    int i0, int j0, int wvx, int lane,
    const bf16x8 qf0, const bf16x8 qf1,
    const bf16* __restrict__ Ebf, const bf16* __restrict__ kb,
    bf16* tst, f32x4 acc_s[8])
{
  const int rbase = i0 + wvx * 16 - j0 - 127;
  f32x4 acc_t[9];
#pragma unroll
  for (int cf = 0; cf < 9; ++cf) {
    int r = rbase + cf * 16 + (lane & 15);
    int re = 2047 - r; re = re < 0 ? 0 : (re > 2047 ? 2047 : re);
    const bf16* ep = Ebf + (size_t)re * 64 + (lane >> 4) * 8;
    f32x4 a = (f32x4){0.f, 0.f, 0.f, 0.f};
    a = MFMA16(qf0, *(const bf16x8*)ep, a, 0, 0, 0);
    a = MFMA16(qf1, *(const bf16x8*)(ep + 32), a, 0, 0, 0);
    acc_t[cf] = a;
  }
#pragma unroll
  for (int cf = 0; cf < 8; ++cf) {
    const bf16* kp = kb + (size_t)(j0 + cf * 16 + (lane & 15)) * 64 + (lane >> 4) * 8;
    f32x4 a = (f32x4){0.f, 0.f, 0.f, 0.f};
    a = MFMA16(qf0, *(const bf16x8*)kp, a, 0, 0, 0);
    a = MFMA16(qf1, *(const bf16x8*)(kp + 32), a, 0, 0, 0);
    acc_s[cf] = a;
  }
  // T strip store (bf16) then diagonal gather
#pragma unroll
  for (int cf = 0; cf < 9; ++cf)
#pragma unroll
    for (int r = 0; r < 4; ++r)
      tst[(4 * (lane >> 4) + r) * TW + cf * 16 + (lane & 15)] = (bf16)acc_t[cf][r];
#pragma unroll
  for (int cf = 0; cf < 8; ++cf) {
    int kl = cf * 16 + (lane & 15);
#pragma unroll
    for (int r = 0; r < 4; ++r) {
      int qw = 4 * (lane >> 4) + r;
      float t = (float)tst[qw * TW + (qw - kl + 127)];
      float vv = (acc_s[cf][r] + t) * 0.125f;
      if (j0 + kl > i0 + wvx * 16 + qw) vv = MASKV;
      acc_s[cf][r] = vv;
    }
  }
}

__global__ __launch_bounds__(256, 3)
void attn_kernel(const bf16* __restrict__ qh, const bf16* __restrict__ kh,
                 const bf16* __restrict__ vt, const bf16* __restrict__ Ebf,
                 float* __restrict__ attn_out, bf16* __restrict__ oh)
{
  __shared__ __align__(16) char lds_t[4 * 16 * TW * 2];  // per-wave T/P strip (bf16)

  const int tid = threadIdx.x, lane = tid & 63, wvx = tid >> 6;
  // XCD-aware swizzle: same-bh blocks cluster per XCD; heavy q-tiles first
  const int n   = blockIdx.x;
  const int xcd = n & 7;
  const int m   = n >> 3;                 // 0..63
  const int bh  = 2 * xcd + (m & 1);
  const int qt  = 31 - (m >> 1);
  const int i0  = qt * BQ;

  const bf16* qb = qh + (size_t)bh * Lq * 64;
  const bf16* kb = kh + (size_t)bh * Lq * 64;
  const bf16* vb = vt + (size_t)bh * 64 * Lq;
  float* attn_b = attn_out + (size_t)bh * Lq * Lq;
  bf16* tst = (bf16*)(lds_t + wvx * (16 * TW * 2));   // T strip (16 x TW)
  bf16* pst = tst;                                    // P strip alias (16 x 128, swz)

  const int qrow = i0 + wvx * 16 + (lane & 15);
  const bf16x8 qf0 = *(const bf16x8*)(qb + (size_t)qrow * 64 + (lane >> 4) * 8);
  const bf16x8 qf1 = *(const bf16x8*)(qb + (size_t)qrow * 64 + 32 + (lane >> 4) * 8);

  const int njt = (i0 + BQ - 1) / BKt + 1;
  f32x4 acc_s[8];

  // ---- PASS 1: row sums of exp(logit) (no max subtraction; logits are small)
  float s_acc[4] = {0.f, 0.f, 0.f, 0.f};
  for (int jt = 0; jt < njt; ++jt) {
    attn_logits2(i0, jt * BKt, wvx, lane, qf0, qf1, Ebf, kb, tst, acc_s);
#pragma unroll
    for (int r = 0; r < 4; ++r) {
      float ps = 0.f;
#pragma unroll
      for (int cf = 0; cf < 8; ++cf) ps += __expf(acc_s[cf][r]);
      s_acc[r] += ps;
    }
  }
  float inv_s[4];
#pragma unroll
  for (int r = 0; r < 4; ++r) {
    float s = s_acc[r];
    for (int d = 1; d < 16; d <<= 1) s += __shfl_xor(s, d);
    inv_s[r] = 1.f / s;
  }

  f32x4 acc_o[4];
#pragma unroll
  for (int nn = 0; nn < 4; ++nn) acc_o[nn] = (f32x4){0.f, 0.f, 0.f, 0.f};

  // ---- PASS 2: recompute logits, write normalized attn (fp32), O += P.V ----
  for (int jt = 0; jt < Lq / BKt; ++jt) {
    const int j0 = jt * BKt;
    if (j0 >= i0 + BQ) {          // fully masked tile -> zeros
#pragma unroll
      for (int it = 0; it < 4; ++it) {
        int qw = it * 4 + (lane >> 4);
        float* dst = attn_b + (size_t)(i0 + wvx * 16 + qw) * Lq + j0 + (lane & 15) * 8;
        *(float4*)dst = make_float4(0.f, 0.f, 0.f, 0.f);
        *(float4*)(dst + 4) = make_float4(0.f, 0.f, 0.f, 0.f);
      }
      continue;
    }
    attn_logits2(i0, j0, wvx, lane, qf0, qf1, Ebf, kb, tst, acc_s);
    // exp, write attn fp32 directly, stash bf16 P into swizzled strip
#pragma unroll
    for (int cf = 0; cf < 8; ++cf) {
      int kl = cf * 16 + (lane & 15);
      int c  = kl >> 3;
#pragma unroll
      for (int r = 0; r < 4; ++r) {
        int qw = 4 * (lane >> 4) + r;
        float p = __expf(acc_s[cf][r]) * inv_s[r];
        attn_b[(size_t)(i0 + wvx * 16 + qw) * Lq + j0 + kl] = p;
        pst[qw * 128 + ((c ^ (qw & 7)) * 8) + (kl & 7)] = (bf16)p;
      }
    }
    // O += P.V  (P A-frags from strip, V B-frags direct from global)
#pragma unroll
    for (int kc = 0; kc < 4; ++kc) {
      int qa = lane & 15;
      int c  = kc * 4 + (lane >> 4);
      bf16x8 pf = *(const bf16x8*)(pst + qa * 128 + ((c ^ (qa & 7)) * 8));
#pragma unroll
      for (int nn = 0; nn < 4; ++nn) {
        const bf16* vp = vb + (size_t)(nn * 16 + (lane & 15)) * Lq + j0 + kc * 32 + (lane >> 4) * 8;
        acc_o[nn] = MFMA16(pf, *(const bf16x8*)vp, acc_o[nn], 0, 0, 0);
      }
    }
  }

  const int b = bh >> 3, h = bh & 7;
#pragma unroll
  for (int nn = 0; nn < 4; ++nn)
#pragma unroll
    for (int r = 0; r < 4; ++r) {
      int qw = 4 * (lane >> 4) + r;
      int ig = i0 + wvx * 16 + qw;
      int col = h * 64 + nn * 16 + (lane & 15);
      oh[(size_t)(b * 2048 + ig) * 512 + col] = (bf16)acc_o[nn][r];
    }
}

// ---------------------------------------------------------------------------
extern "C" void kernel_launch(void* const* d_in, const int* in_sizes, int n_in,
                              void* d_out, int out_size, void* d_ws, size_t ws_size,
                              hipStream_t stream) {
  const float* q    = (const float*)d_in[0];
  const float* k    = (const float*)d_in[1];
  const float* v    = (const float*)d_in[2];
  const float* wq   = (const float*)d_in[3];
  const float* wq_b = (const float*)d_in[4];
  const float* wk   = (const float*)d_in[5];
  const float* wk_b = (const float*)d_in[6];
  const float* wv   = (const float*)d_in[7];
  const float* wv_b = (const float*)d_in[8];
  const float* fc   = (const float*)d_in[9];
  const float* fc_b = (const float*)d_in[10];
  const float* E    = (const float*)d_in[11];

  if (ws_size < 31719424) return;  // workspace layout below needs ~30.3 MiB
  char* ws = (char*)d_ws;
  bf16* q_bf  = (bf16*)(ws);
  bf16* k_bf  = (bf16*)(ws + 4194304);
  bf16* v_bf  = (bf16*)(ws + 8388608);
  bf16* wq_bf = (bf16*)(ws + 12582912);
  bf16* wk_bf = (bf16*)(ws + 13107200);
  bf16* wv_bf = (bf16*)(ws + 13631488);
  bf16* fc_bf = (bf16*)(ws + 14155776);
  bf16* E_bf  = (bf16*)(ws + 14680064);
  bf16* qh_bf = (bf16*)(ws + 14942208);
  bf16* kh_bf = (bf16*)(ws + 19136512);
  bf16* vt_bf = (bf16*)(ws + 23330816);
  bf16* oh_bf = (bf16*)(ws + 27525120);

  float* out_f  = (float*)d_out;
  float* attn_f = out_f + 2097152;

  convert_all<<<7296, 256, 0, stream>>>(q, k, v, wq, wk, wv, fc, E,
      q_bf, k_bf, v_bf, wq_bf, wk_bf, wv_bf, fc_bf, E_bf);
  gemm512<0><<<dim3(32, 4), 256, 0, stream>>>(q_bf, wq_bf, wq_b, qh_bf);
  gemm512<0><<<dim3(32, 4), 256, 0, stream>>>(k_bf, wk_bf, wk_b, kh_bf);
  gemm512<2><<<dim3(4, 32), 256, 0, stream>>>(wv_bf, v_bf, wv_b, vt_bf);
  attn_kernel<<<512, 256, 0, stream>>>(qh_bf, kh_bf, vt_bf, E_bf, attn_f, oh_bf);
  gemm512<3><<<dim3(32, 4), 256, 0, stream>>>(oh_bf, fc_bf, fc_b, out_f);
}

// Round 3
// 232.381 us; speedup vs baseline: 2.1514x; 2.1514x over previous
//
#include <hip/hip_runtime.h>
#include <hip/hip_bf16.h>
#include <cstdint>

typedef __bf16 bf16;
typedef __attribute__((ext_vector_type(8))) __bf16 bf16x8;
typedef __attribute__((ext_vector_type(4))) __bf16 bf16x4;
typedef __attribute__((ext_vector_type(4))) float f32x4;

#define MFMA16 __builtin_amdgcn_mfma_f32_16x16x32_bf16
#define MASKV (-1e30f)

static constexpr int Lq  = 2048;
static constexpr int BQ  = 64;    // q rows per workgroup (16 per wave)
static constexpr int BKt = 64;    // keys per tile
static constexpr int TW  = 84;    // T strip stride (bf16): 79 used; 42-dword rows
                                  // -> row groups {r,r+4,r+8,r+12} hit distinct bank octets

__device__ __forceinline__ void async_load16(const void* g, void* l) {
  __builtin_amdgcn_global_load_lds(
      (__attribute__((address_space(1))) void*)g,
      (__attribute__((address_space(3))) void*)l, 16, 0, 0);
}

// ---------------------------------------------------------------------------
// fp32 -> bf16 conversion of all inputs
// ---------------------------------------------------------------------------
__global__ void convert_all(const float* __restrict__ q, const float* __restrict__ k,
                            const float* __restrict__ v, const float* __restrict__ wq,
                            const float* __restrict__ wk, const float* __restrict__ wv,
                            const float* __restrict__ fc, const float* __restrict__ E,
                            bf16* q_bf, bf16* k_bf, bf16* v_bf, bf16* wq_bf,
                            bf16* wk_bf, bf16* wv_bf, bf16* fc_bf, bf16* E_bf)
{
  int i = blockIdx.x * blockDim.x + threadIdx.x;   // vec4 index
  const float* src; bf16* dst; int rel;
  if      (i < 524288)  { src = q;  dst = q_bf;  rel = i; }
  else if (i < 1048576) { src = k;  dst = k_bf;  rel = i - 524288; }
  else if (i < 1572864) { src = v;  dst = v_bf;  rel = i - 1048576; }
  else if (i < 1638400) { src = wq; dst = wq_bf; rel = i - 1572864; }
  else if (i < 1703936) { src = wk; dst = wk_bf; rel = i - 1638400; }
  else if (i < 1769472) { src = wv; dst = wv_bf; rel = i - 1703936; }
  else if (i < 1835008) { src = fc; dst = fc_bf; rel = i - 1769472; }
  else if (i < 1867776) { src = E;  dst = E_bf;  rel = i - 1835008; }
  else return;
  float4 x = *(const float4*)(src + (size_t)rel * 4);
  bf16x4 o;
  o[0] = (bf16)x.x; o[1] = (bf16)x.y; o[2] = (bf16)x.z; o[3] = (bf16)x.w;
  *(bf16x4*)(dst + (size_t)rel * 4) = o;
}

// ---------------------------------------------------------------------------
// Generic 128x128-tile bf16 GEMM, C[i][j] = sum_k A[i][k]*B[j][k] + bias
// MODE 0: C bf16 (B,H,L,DH) ; MODE 2: C bf16 (B,H,DH,L), bias[i] ; MODE 3: fp32
// ---------------------------------------------------------------------------
template<int MODE>
__global__ __launch_bounds__(256, 2)
void gemm512(const bf16* __restrict__ A, const bf16* __restrict__ Bm,
             const float* __restrict__ bias, void* __restrict__ Cv)
{
  __shared__ __align__(16) char lA[16384];
  __shared__ __align__(16) char lB[16384];
  const int tid = threadIdx.x, lane = tid & 63, wv = tid >> 6;
  const int wr = wv >> 1, wc = wv & 1;
  const int tm = blockIdx.x, tn = blockIdx.y;

  f32x4 acc[4][4];
#pragma unroll
  for (int m = 0; m < 4; ++m)
#pragma unroll
    for (int n = 0; n < 4; ++n) acc[m][n] = (f32x4){0.f, 0.f, 0.f, 0.f};

  for (int k0 = 0; k0 < 512; k0 += 64) {
    __syncthreads();
#pragma unroll
    for (int it = 0; it < 4; ++it) {
      int slot = it * 256 + wv * 64 + lane;
      int row = slot >> 3, c = slot & 7;
      int gk = k0 + ((c ^ (row & 7)) * 8);
      async_load16(A  + (size_t)(tm * 128 + row) * 512 + gk, lA + (it * 256 + wv * 64) * 16);
      async_load16(Bm + (size_t)(tn * 128 + row) * 512 + gk, lB + (it * 256 + wv * 64) * 16);
    }
    __syncthreads();
#pragma unroll
    for (int kc = 0; kc < 2; ++kc) {
      bf16x8 af[4], bfr[4];
#pragma unroll
      for (int m = 0; m < 4; ++m) {
        int row = wr * 64 + m * 16 + (lane & 15);
        int ch = ((lane >> 4) + kc * 4) ^ (row & 7);
        af[m] = *(const bf16x8*)(lA + row * 128 + ch * 16);
      }
#pragma unroll
      for (int n = 0; n < 4; ++n) {
        int row = wc * 64 + n * 16 + (lane & 15);
        int ch = ((lane >> 4) + kc * 4) ^ (row & 7);
        bfr[n] = *(const bf16x8*)(lB + row * 128 + ch * 16);
      }
#pragma unroll
      for (int m = 0; m < 4; ++m)
#pragma unroll
        for (int n = 0; n < 4; ++n)
          acc[m][n] = MFMA16(af[m], bfr[n], acc[m][n], 0, 0, 0);
    }
  }

#pragma unroll
  for (int m = 0; m < 4; ++m)
#pragma unroll
    for (int n = 0; n < 4; ++n)
#pragma unroll
      for (int r = 0; r < 4; ++r) {
        int gi = tm * 128 + wr * 64 + m * 16 + 4 * (lane >> 4) + r;
        int gj = tn * 128 + wc * 64 + n * 16 + (lane & 15);
        float vv = acc[m][n][r] + ((MODE == 2) ? bias[gi] : bias[gj]);
        if (MODE == 3) {
          ((float*)Cv)[(size_t)gi * 512 + gj] = vv;
        } else if (MODE == 2) {
          int h = gi >> 6, dh = gi & 63, b = gj >> 11, l = gj & 2047;
          ((bf16*)Cv)[((size_t)((b * 8 + h) * 64 + dh)) * 2048 + l] = (bf16)vv;
        } else {
          int b = gi >> 11, l = gi & 2047, h = gj >> 6, dh = gj & 63;
          ((bf16*)Cv)[((size_t)((b * 8 + h) * 2048 + l)) * 64 + dh] = (bf16)vv;
        }
      }
}

// ---------------------------------------------------------------------------
// Attention helpers
// ---------------------------------------------------------------------------
// Stage a 64-key x 64-dh K tile (rows 128B, 8 swizzled 16B chunks) : 2 insts/thread
__device__ __forceinline__ void stage_k(const bf16* __restrict__ kb, int j0,
                                        char* dst, int tid) {
#pragma unroll
  for (int it = 0; it < 2; ++it) {
    int slot = it * 256 + tid;
    int row = slot >> 3, c = slot & 7;
    async_load16(kb + (size_t)(j0 + row) * 64 + ((c ^ (row & 7)) * 8), dst + slot * 16);
  }
}
// Stage a 64-dh x 64-key V tile from vt ([dh][l] layout)
__device__ __forceinline__ void stage_v(const bf16* __restrict__ vb, int j0,
                                        char* dst, int tid) {
#pragma unroll
  for (int it = 0; it < 2; ++it) {
    int slot = it * 256 + tid;
    int row = slot >> 3, c = slot & 7;
    async_load16(vb + (size_t)row * Lq + j0 + ((c ^ (row & 7)) * 8), dst + slot * 16);
  }
}

// Logits for one 16q x 64k tile: acc_s = (QK + Srel)/8, masked entries = MASKV.
__device__ __forceinline__ void attn_logits3(
    int i0, int j0, int wvx, int lane,
    const bf16x8 qf0, const bf16x8 qf1,
    const bf16* __restrict__ Ebf, const char* lk, bf16* tst, f32x4 acc_s[4])
{
  const int rbase = i0 + wvx * 16 - j0 - 63;
  f32x4 acc_t[5];
#pragma unroll
  for (int cf = 0; cf < 5; ++cf) {
    int r = rbase + cf * 16 + (lane & 15);
    int re = 2047 - r; re = re < 0 ? 0 : (re > 2047 ? 2047 : re);
    const bf16* ep = Ebf + (size_t)re * 64 + (lane >> 4) * 8;
    f32x4 a = (f32x4){0.f, 0.f, 0.f, 0.f};
    a = MFMA16(qf0, *(const bf16x8*)ep, a, 0, 0, 0);
    a = MFMA16(qf1, *(const bf16x8*)(ep + 32), a, 0, 0, 0);
    acc_t[cf] = a;
  }
#pragma unroll
  for (int cf = 0; cf < 4; ++cf) {
    int key = cf * 16 + (lane & 15);
    int c0 = (lane >> 4) ^ (key & 7);
    int c1 = ((lane >> 4) + 4) ^ (key & 7);
    f32x4 a = (f32x4){0.f, 0.f, 0.f, 0.f};
    a = MFMA16(qf0, *(const bf16x8*)(lk + key * 128 + c0 * 16), a, 0, 0, 0);
    a = MFMA16(qf1, *(const bf16x8*)(lk + key * 128 + c1 * 16), a, 0, 0, 0);
    acc_s[cf] = a;
  }
#pragma unroll
  for (int cf = 0; cf < 5; ++cf)
#pragma unroll
    for (int r = 0; r < 4; ++r)
      tst[(4 * (lane >> 4) + r) * TW + cf * 16 + (lane & 15)] = (bf16)acc_t[cf][r];
  asm volatile("s_waitcnt lgkmcnt(0)" ::: "memory");
  __builtin_amdgcn_sched_barrier(0);
#pragma unroll
  for (int cf = 0; cf < 4; ++cf) {
    int kl = cf * 16 + (lane & 15);
#pragma unroll
    for (int r = 0; r < 4; ++r) {
      int qw = 4 * (lane >> 4) + r;
      float t = (float)tst[qw * TW + (qw - kl + 63)];
      float vv = (acc_s[cf][r] + t) * 0.125f;
      if (j0 + kl > i0 + wvx * 16 + qw) vv = MASKV;
      acc_s[cf][r] = vv;
    }
  }
}

__global__ __launch_bounds__(256, 2)
void attn_kernel(const bf16* __restrict__ qh, const bf16* __restrict__ kh,
                 const bf16* __restrict__ vt, const bf16* __restrict__ Ebf,
                 float* __restrict__ attn_out, bf16* __restrict__ oh)
{
  __shared__ __align__(16) char lds_k[2][64 * 128];   // dbuf K tiles
  __shared__ __align__(16) char lds_v[2][64 * 128];   // dbuf V tiles
  __shared__ __align__(16) char lds_t[4][16 * TW * 2];// per-wave T / P strip

  const int tid = threadIdx.x, lane = tid & 63, wvx = tid >> 6;
  // XCD swizzle by bh; heavy/light qt pairing for load balance
  const int n   = blockIdx.x;
  const int xcd = n & 7;
  const int m   = n >> 3;                // 0..63
  const int bh  = 2 * xcd + (m & 1);
  const int mm  = m >> 1;                // 0..31
  const int qt  = (mm & 1) ? (mm >> 1) : (31 - (mm >> 1));
  const int i0  = qt * BQ;

  const bf16* qb = qh + (size_t)bh * Lq * 64;
  const bf16* kb = kh + (size_t)bh * Lq * 64;
  const bf16* vb = vt + (size_t)bh * 64 * Lq;
  float* attn_b = attn_out + (size_t)bh * Lq * Lq;
  bf16* tst = (bf16*)lds_t[wvx];
  bf16* pst = tst;                       // P strip alias (16 x 64, swizzled)

  const int qrow = i0 + wvx * 16 + (lane & 15);
  const bf16x8 qf0 = *(const bf16x8*)(qb + (size_t)qrow * 64 + (lane >> 4) * 8);
  const bf16x8 qf1 = *(const bf16x8*)(qb + (size_t)qrow * 64 + 32 + (lane >> 4) * 8);

  f32x4 acc_s[4];

  // ---- PASS 1: row sums of exp(logit), K staged w/ double buffer ----
  float s_acc[4] = {0.f, 0.f, 0.f, 0.f};
  stage_k(kb, 0, lds_k[0], tid);
  __syncthreads();
  for (int jt = 0; jt <= qt; ++jt) {
    if (jt < qt) stage_k(kb, (jt + 1) * BKt, lds_k[(jt + 1) & 1], tid);
    attn_logits3(i0, jt * BKt, wvx, lane, qf0, qf1, Ebf, lds_k[jt & 1], tst, acc_s);
#pragma unroll
    for (int r = 0; r < 4; ++r) {
      float ps = 0.f;
#pragma unroll
      for (int cf = 0; cf < 4; ++cf) ps += __expf(acc_s[cf][r]);
      s_acc[r] += ps;
    }
    __syncthreads();
  }
  float inv_s[4];
#pragma unroll
  for (int r = 0; r < 4; ++r) {
    float s = s_acc[r];
    for (int d = 1; d < 16; d <<= 1) s += __shfl_xor(s, d);
    inv_s[r] = 1.f / s;
  }

  f32x4 acc_o[4];
#pragma unroll
  for (int nn = 0; nn < 4; ++nn) acc_o[nn] = (f32x4){0.f, 0.f, 0.f, 0.f};

  // ---- PASS 2: recompute, write attn, O += P.V (K+V dbuf) ----
  stage_k(kb, 0, lds_k[0], tid);
  stage_v(vb, 0, lds_v[0], tid);
  __syncthreads();
  for (int jt = 0; jt <= qt; ++jt) {
    const int j0 = jt * BKt;
    if (jt < qt) {
      stage_k(kb, j0 + BKt, lds_k[(jt + 1) & 1], tid);
      stage_v(vb, j0 + BKt, lds_v[(jt + 1) & 1], tid);
    }
    attn_logits3(i0, j0, wvx, lane, qf0, qf1, Ebf, lds_k[jt & 1], tst, acc_s);
    asm volatile("" ::: "memory");   // order P writes after T gathers
    // P -> swizzled strip (bf16)
#pragma unroll
    for (int cf = 0; cf < 4; ++cf) {
      int kl = cf * 16 + (lane & 15);
      int chs = kl >> 3;
#pragma unroll
      for (int r = 0; r < 4; ++r) {
        int qw = 4 * (lane >> 4) + r;
        float p = __expf(acc_s[cf][r]) * inv_s[r];
        pst[qw * 64 + ((chs ^ (qw & 7)) * 8) + (kl & 7)] = (bf16)p;
      }
    }
    asm volatile("s_waitcnt lgkmcnt(0)" ::: "memory");
    __builtin_amdgcn_sched_barrier(0);
    // attn write: 256B-contiguous per 8-lane group
#pragma unroll
    for (int it = 0; it < 2; ++it) {
      int qw = it * 8 + (lane >> 3);
      int c = lane & 7;
      bf16x8 pv = *(const bf16x8*)(pst + qw * 64 + ((c ^ (qw & 7)) * 8));
      float* dst = attn_b + (size_t)(i0 + wvx * 16 + qw) * Lq + j0 + c * 8;
      float4 f0, f1;
      f0.x = (float)pv[0]; f0.y = (float)pv[1]; f0.z = (float)pv[2]; f0.w = (float)pv[3];
      f1.x = (float)pv[4]; f1.y = (float)pv[5]; f1.z = (float)pv[6]; f1.w = (float)pv[7];
      *(float4*)dst = f0; *(float4*)(dst + 4) = f1;
    }
    // O += P.V
#pragma unroll
    for (int kc = 0; kc < 2; ++kc) {
      int qa = lane & 15;
      int cha = (kc * 4 + (lane >> 4)) ^ (qa & 7);
      bf16x8 pf = *(const bf16x8*)(pst + qa * 64 + cha * 8);
#pragma unroll
      for (int nn = 0; nn < 4; ++nn) {
        int dh = nn * 16 + (lane & 15);
        int chv = (kc * 4 + (lane >> 4)) ^ (dh & 7);
        bf16x8 vf = *(const bf16x8*)(lds_v[jt & 1] + dh * 128 + chv * 16);
        acc_o[nn] = MFMA16(pf, vf, acc_o[nn], 0, 0, 0);
      }
    }
    __syncthreads();
  }

  // ---- zero-fill masked tiles: pure stores, no barriers ----
  for (int jt = qt + 1; jt < Lq / BKt; ++jt) {
    const int j0 = jt * BKt;
#pragma unroll
    for (int it = 0; it < 2; ++it) {
      int qw = it * 8 + (lane >> 3);
      float* dst = attn_b + (size_t)(i0 + wvx * 16 + qw) * Lq + j0 + (lane & 7) * 8;
      *(float4*)dst = make_float4(0.f, 0.f, 0.f, 0.f);
      *(float4*)(dst + 4) = make_float4(0.f, 0.f, 0.f, 0.f);
    }
  }

  const int b = bh >> 3, h = bh & 7;
#pragma unroll
  for (int nn = 0; nn < 4; ++nn)
#pragma unroll
    for (int r = 0; r < 4; ++r) {
      int qw = 4 * (lane >> 4) + r;
      int ig = i0 + wvx * 16 + qw;
      int col = h * 64 + nn * 16 + (lane & 15);
      oh[(size_t)(b * 2048 + ig) * 512 + col] = (bf16)acc_o[nn][r];
    }
}

// ---------------------------------------------------------------------------
extern "C" void kernel_launch(void* const* d_in, const int* in_sizes, int n_in,
                              void* d_out, int out_size, void* d_ws, size_t ws_size,
                              hipStream_t stream) {
  const float* q    = (const float*)d_in[0];
  const float* k    = (const float*)d_in[1];
  const float* v    = (const float*)d_in[2];
  const float* wq   = (const float*)d_in[3];
  const float* wq_b = (const float*)d_in[4];
  const float* wk   = (const float*)d_in[5];
  const float* wk_b = (const float*)d_in[6];
  const float* wv   = (const float*)d_in[7];
  const float* wv_b = (const float*)d_in[8];
  const float* fc   = (const float*)d_in[9];
  const float* fc_b = (const float*)d_in[10];
  const float* E    = (const float*)d_in[11];

  if (ws_size < 31719424) return;  // workspace layout below needs ~30.3 MiB
  char* ws = (char*)d_ws;
  bf16* q_bf  = (bf16*)(ws);
  bf16* k_bf  = (bf16*)(ws + 4194304);
  bf16* v_bf  = (bf16*)(ws + 8388608);
  bf16* wq_bf = (bf16*)(ws + 12582912);
  bf16* wk_bf = (bf16*)(ws + 13107200);
  bf16* wv_bf = (bf16*)(ws + 13631488);
  bf16* fc_bf = (bf16*)(ws + 14155776);
  bf16* E_bf  = (bf16*)(ws + 14680064);
  bf16* qh_bf = (bf16*)(ws + 14942208);
  bf16* kh_bf = (bf16*)(ws + 19136512);
  bf16* vt_bf = (bf16*)(ws + 23330816);
  bf16* oh_bf = (bf16*)(ws + 27525120);

  float* out_f  = (float*)d_out;
  float* attn_f = out_f + 2097152;

  convert_all<<<7296, 256, 0, stream>>>(q, k, v, wq, wk, wv, fc, E,
      q_bf, k_bf, v_bf, wq_bf, wk_bf, wv_bf, fc_bf, E_bf);
  gemm512<0><<<dim3(32, 4), 256, 0, stream>>>(q_bf, wq_bf, wq_b, qh_bf);
  gemm512<0><<<dim3(32, 4), 256, 0, stream>>>(k_bf, wk_bf, wk_b, kh_bf);
  gemm512<2><<<dim3(4, 32), 256, 0, stream>>>(wv_bf, v_bf, wv_b, vt_bf);
  attn_kernel<<<512, 256, 0, stream>>>(qh_bf, kh_bf, vt_bf, E_bf, attn_f, oh_bf);
  gemm512<3><<<dim3(32, 4), 256, 0, stream>>>(oh_bf, fc_bf, fc_b, out_f);
}

// Round 4
// 222.090 us; speedup vs baseline: 2.2511x; 1.0463x over previous
//
#include <hip/hip_runtime.h>
#include <hip/hip_bf16.h>
#include <cstdint>

typedef __bf16 bf16;
typedef __attribute__((ext_vector_type(8))) __bf16 bf16x8;
typedef __attribute__((ext_vector_type(4))) __bf16 bf16x4;
typedef __attribute__((ext_vector_type(4))) float f32x4;

#define MFMA16 __builtin_amdgcn_mfma_f32_16x16x32_bf16
#define MASKV (-1e30f)

static constexpr int Lq  = 2048;
static constexpr int BQ  = 64;    // q rows per workgroup (16 per wave)
static constexpr int BKt = 64;    // keys per tile
static constexpr int TW  = 84;    // T strip stride (bf16): 79 used; 42-dword rows

__device__ __forceinline__ void async_load16(const void* g, void* l) {
  __builtin_amdgcn_global_load_lds(
      (__attribute__((address_space(1))) void*)g,
      (__attribute__((address_space(3))) void*)l, 16, 0, 0);
}

// ---------------------------------------------------------------------------
// fp32 -> bf16 conversion of all inputs
// ---------------------------------------------------------------------------
__global__ void convert_all(const float* __restrict__ q, const float* __restrict__ k,
                            const float* __restrict__ v, const float* __restrict__ wq,
                            const float* __restrict__ wk, const float* __restrict__ wv,
                            const float* __restrict__ fc, const float* __restrict__ E,
                            bf16* q_bf, bf16* k_bf, bf16* v_bf, bf16* wq_bf,
                            bf16* wk_bf, bf16* wv_bf, bf16* fc_bf, bf16* E_bf)
{
  int i = blockIdx.x * blockDim.x + threadIdx.x;   // vec4 index
  const float* src; bf16* dst; int rel;
  if      (i < 524288)  { src = q;  dst = q_bf;  rel = i; }
  else if (i < 1048576) { src = k;  dst = k_bf;  rel = i - 524288; }
  else if (i < 1572864) { src = v;  dst = v_bf;  rel = i - 1048576; }
  else if (i < 1638400) { src = wq; dst = wq_bf; rel = i - 1572864; }
  else if (i < 1703936) { src = wk; dst = wk_bf; rel = i - 1638400; }
  else if (i < 1769472) { src = wv; dst = wv_bf; rel = i - 1703936; }
  else if (i < 1835008) { src = fc; dst = fc_bf; rel = i - 1769472; }
  else if (i < 1867776) { src = E;  dst = E_bf;  rel = i - 1835008; }
  else return;
  float4 x = *(const float4*)(src + (size_t)rel * 4);
  bf16x4 o;
  o[0] = (bf16)x.x; o[1] = (bf16)x.y; o[2] = (bf16)x.z; o[3] = (bf16)x.w;
  *(bf16x4*)(dst + (size_t)rel * 4) = o;
}

// ---------------------------------------------------------------------------
// Generic 128x128-tile bf16 GEMM, C[i][j] = sum_k A[i][k]*B[j][k] + bias
// MODE 0: C bf16 (B,H,L,DH) ; MODE 2: C bf16 (B,H,DH,L), bias[i] ; MODE 3: fp32
// ---------------------------------------------------------------------------
template<int MODE>
__global__ __launch_bounds__(256, 2)
void gemm512(const bf16* __restrict__ A, const bf16* __restrict__ Bm,
             const float* __restrict__ bias, void* __restrict__ Cv)
{
  __shared__ __align__(16) char lA[16384];
  __shared__ __align__(16) char lB[16384];
  const int tid = threadIdx.x, lane = tid & 63, wv = tid >> 6;
  const int wr = wv >> 1, wc = wv & 1;
  const int tm = blockIdx.x, tn = blockIdx.y;

  f32x4 acc[4][4];
#pragma unroll
  for (int m = 0; m < 4; ++m)
#pragma unroll
    for (int n = 0; n < 4; ++n) acc[m][n] = (f32x4){0.f, 0.f, 0.f, 0.f};

  for (int k0 = 0; k0 < 512; k0 += 64) {
    __syncthreads();
#pragma unroll
    for (int it = 0; it < 4; ++it) {
      int slot = it * 256 + wv * 64 + lane;
      int row = slot >> 3, c = slot & 7;
      int gk = k0 + ((c ^ (row & 7)) * 8);
      async_load16(A  + (size_t)(tm * 128 + row) * 512 + gk, lA + (it * 256 + wv * 64) * 16);
      async_load16(Bm + (size_t)(tn * 128 + row) * 512 + gk, lB + (it * 256 + wv * 64) * 16);
    }
    __syncthreads();
#pragma unroll
    for (int kc = 0; kc < 2; ++kc) {
      bf16x8 af[4], bfr[4];
#pragma unroll
      for (int m = 0; m < 4; ++m) {
        int row = wr * 64 + m * 16 + (lane & 15);
        int ch = ((lane >> 4) + kc * 4) ^ (row & 7);
        af[m] = *(const bf16x8*)(lA + row * 128 + ch * 16);
      }
#pragma unroll
      for (int n = 0; n < 4; ++n) {
        int row = wc * 64 + n * 16 + (lane & 15);
        int ch = ((lane >> 4) + kc * 4) ^ (row & 7);
        bfr[n] = *(const bf16x8*)(lB + row * 128 + ch * 16);
      }
#pragma unroll
      for (int m = 0; m < 4; ++m)
#pragma unroll
        for (int n = 0; n < 4; ++n)
          acc[m][n] = MFMA16(af[m], bfr[n], acc[m][n], 0, 0, 0);
    }
  }

#pragma unroll
  for (int m = 0; m < 4; ++m)
#pragma unroll
    for (int n = 0; n < 4; ++n)
#pragma unroll
      for (int r = 0; r < 4; ++r) {
        int gi = tm * 128 + wr * 64 + m * 16 + 4 * (lane >> 4) + r;
        int gj = tn * 128 + wc * 64 + n * 16 + (lane & 15);
        float vv = acc[m][n][r] + ((MODE == 2) ? bias[gi] : bias[gj]);
        if (MODE == 3) {
          ((float*)Cv)[(size_t)gi * 512 + gj] = vv;
        } else if (MODE == 2) {
          int h = gi >> 6, dh = gi & 63, b = gj >> 11, l = gj & 2047;
          ((bf16*)Cv)[((size_t)((b * 8 + h) * 64 + dh)) * 2048 + l] = (bf16)vv;
        } else {
          int b = gi >> 11, l = gi & 2047, h = gj >> 6, dh = gj & 63;
          ((bf16*)Cv)[((size_t)((b * 8 + h) * 2048 + l)) * 64 + dh] = (bf16)vv;
        }
      }
}

// ---------------------------------------------------------------------------
// Attention helpers
// ---------------------------------------------------------------------------
__device__ __forceinline__ void stage_k(const bf16* __restrict__ kb, int j0,
                                        char* dst, int tid) {
#pragma unroll
  for (int it = 0; it < 2; ++it) {
    int slot = it * 256 + tid;
    int row = slot >> 3, c = slot & 7;
    async_load16(kb + (size_t)(j0 + row) * 64 + ((c ^ (row & 7)) * 8), dst + slot * 16);
  }
}
__device__ __forceinline__ void stage_v(const bf16* __restrict__ vb, int j0,
                                        char* dst, int tid) {
#pragma unroll
  for (int it = 0; it < 2; ++it) {
    int slot = it * 256 + tid;
    int row = slot >> 3, c = slot & 7;
    async_load16(vb + (size_t)row * Lq + j0 + ((c ^ (row & 7)) * 8), dst + slot * 16);
  }
}

// Logits for one 16q x 64k tile: acc_s = (QK + Srel)/8, masked entries = MASKV.
__device__ __forceinline__ void attn_logits3(
    int i0, int j0, int wvx, int lane,
    const bf16x8 qf0, const bf16x8 qf1,
    const bf16* __restrict__ Ebf, const char* lk, bf16* tst, f32x4 acc_s[4])
{
  const int rbase = i0 + wvx * 16 - j0 - 63;
  f32x4 acc_t[5];
#pragma unroll
  for (int cf = 0; cf < 5; ++cf) {
    int r = rbase + cf * 16 + (lane & 15);
    int re = 2047 - r; re = re < 0 ? 0 : (re > 2047 ? 2047 : re);
    const bf16* ep = Ebf + (size_t)re * 64 + (lane >> 4) * 8;
    f32x4 a = (f32x4){0.f, 0.f, 0.f, 0.f};
    a = MFMA16(qf0, *(const bf16x8*)ep, a, 0, 0, 0);
    a = MFMA16(qf1, *(const bf16x8*)(ep + 32), a, 0, 0, 0);
    acc_t[cf] = a;
  }
#pragma unroll
  for (int cf = 0; cf < 4; ++cf) {
    int key = cf * 16 + (lane & 15);
    int c0 = (lane >> 4) ^ (key & 7);
    int c1 = ((lane >> 4) + 4) ^ (key & 7);
    f32x4 a = (f32x4){0.f, 0.f, 0.f, 0.f};
    a = MFMA16(qf0, *(const bf16x8*)(lk + key * 128 + c0 * 16), a, 0, 0, 0);
    a = MFMA16(qf1, *(const bf16x8*)(lk + key * 128 + c1 * 16), a, 0, 0, 0);
    acc_s[cf] = a;
  }
#pragma unroll
  for (int cf = 0; cf < 5; ++cf)
#pragma unroll
    for (int r = 0; r < 4; ++r)
      tst[(4 * (lane >> 4) + r) * TW + cf * 16 + (lane & 15)] = (bf16)acc_t[cf][r];
  asm volatile("s_waitcnt lgkmcnt(0)" ::: "memory");
  __builtin_amdgcn_sched_barrier(0);
#pragma unroll
  for (int cf = 0; cf < 4; ++cf) {
    int kl = cf * 16 + (lane & 15);
#pragma unroll
    for (int r = 0; r < 4; ++r) {
      int qw = 4 * (lane >> 4) + r;
      float t = (float)tst[qw * TW + (qw - kl + 63)];
      float vv = (acc_s[cf][r] + t) * 0.125f;
      if (j0 + kl > i0 + wvx * 16 + qw) vv = MASKV;
      acc_s[cf][r] = vv;
    }
  }
}

// ---------------------------------------------------------------------------
// Single-pass attention: write UNNORMALIZED exp to attn, accumulate s and
// unnormalized O; then rescale O (epilogue) and attn rows (streaming tail).
// Block mapping: pair (n, n+256) lands on the same CU (round-robin dispatch)
// and gets complementary qt -> every CU does exactly 33 tile-steps + equal tail.
// ---------------------------------------------------------------------------
__global__ __launch_bounds__(256, 2)
void attn_kernel(const bf16* __restrict__ qh, const bf16* __restrict__ kh,
                 const bf16* __restrict__ vt, const bf16* __restrict__ Ebf,
                 float* __restrict__ attn_out, bf16* __restrict__ oh)
{
  __shared__ __align__(16) char lds_k[2][64 * 128];   // dbuf K tiles
  __shared__ __align__(16) char lds_v[2][64 * 128];   // dbuf V tiles
  __shared__ __align__(16) char lds_t[4][16 * TW * 2];// per-wave T / P strip

  const int tid = threadIdx.x, lane = tid & 63, wvx = tid >> 6;
  const int n    = blockIdx.x;
  const int half = n >> 8;               // 0 | 1
  const int r0   = n & 255;
  const int xcd  = r0 & 7;
  const int idx  = r0 >> 3;              // 0..31
  const int bh   = 2 * xcd + half;       // 2 bh per XCD
  const int qt   = half ? idx : 31 - idx;// complementary pairing
  const int i0   = qt * BQ;

  const bf16* qb = qh + (size_t)bh * Lq * 64;
  const bf16* kb = kh + (size_t)bh * Lq * 64;
  const bf16* vb = vt + (size_t)bh * 64 * Lq;
  float* attn_b = attn_out + (size_t)bh * Lq * Lq;
  bf16* tst = (bf16*)lds_t[wvx];
  bf16* pst = tst;                       // P strip alias (16 x 64, swizzled)

  const int qrow = i0 + wvx * 16 + (lane & 15);
  const bf16x8 qf0 = *(const bf16x8*)(qb + (size_t)qrow * 64 + (lane >> 4) * 8);
  const bf16x8 qf1 = *(const bf16x8*)(qb + (size_t)qrow * 64 + 32 + (lane >> 4) * 8);

  f32x4 acc_s[4];
  f32x4 acc_o[4];
  float s_acc[4] = {0.f, 0.f, 0.f, 0.f};
#pragma unroll
  for (int nn = 0; nn < 4; ++nn) acc_o[nn] = (f32x4){0.f, 0.f, 0.f, 0.f};

  stage_k(kb, 0, lds_k[0], tid);
  stage_v(vb, 0, lds_v[0], tid);
  __syncthreads();
  for (int jt = 0; jt <= qt; ++jt) {
    const int j0 = jt * BKt;
    if (jt < qt) {
      stage_k(kb, j0 + BKt, lds_k[(jt + 1) & 1], tid);
      stage_v(vb, j0 + BKt, lds_v[(jt + 1) & 1], tid);
    }
    attn_logits3(i0, j0, wvx, lane, qf0, qf1, Ebf, lds_k[jt & 1], tst, acc_s);
    asm volatile("" ::: "memory");   // order P writes after T gathers
    // exp (unnormalized): accumulate s, stash bf16 P into swizzled strip
#pragma unroll
    for (int cf = 0; cf < 4; ++cf) {
      int kl = cf * 16 + (lane & 15);
      int chs = kl >> 3;
#pragma unroll
      for (int r = 0; r < 4; ++r) {
        int qw = 4 * (lane >> 4) + r;
        float p = __expf(acc_s[cf][r]);
        s_acc[r] += p;
        pst[qw * 64 + ((chs ^ (qw & 7)) * 8) + (kl & 7)] = (bf16)p;
      }
    }
    asm volatile("s_waitcnt lgkmcnt(0)" ::: "memory");
    __builtin_amdgcn_sched_barrier(0);
    // attn write (unnormalized): 256B-contiguous per 8-lane group
#pragma unroll
    for (int it = 0; it < 2; ++it) {
      int qw = it * 8 + (lane >> 3);
      int c = lane & 7;
      bf16x8 pv = *(const bf16x8*)(pst + qw * 64 + ((c ^ (qw & 7)) * 8));
      float* dst = attn_b + (size_t)(i0 + wvx * 16 + qw) * Lq + j0 + c * 8;
      float4 f0, f1;
      f0.x = (float)pv[0]; f0.y = (float)pv[1]; f0.z = (float)pv[2]; f0.w = (float)pv[3];
      f1.x = (float)pv[4]; f1.y = (float)pv[5]; f1.z = (float)pv[6]; f1.w = (float)pv[7];
      *(float4*)dst = f0; *(float4*)(dst + 4) = f1;
    }
    // O += P.V (unnormalized)
#pragma unroll
    for (int kc = 0; kc < 2; ++kc) {
      int qa = lane & 15;
      int cha = (kc * 4 + (lane >> 4)) ^ (qa & 7);
      bf16x8 pf = *(const bf16x8*)(pst + qa * 64 + cha * 8);
#pragma unroll
      for (int nn = 0; nn < 4; ++nn) {
        int dh = nn * 16 + (lane & 15);
        int chv = (kc * 4 + (lane >> 4)) ^ (dh & 7);
        bf16x8 vf = *(const bf16x8*)(lds_v[jt & 1] + dh * 128 + chv * 16);
        acc_o[nn] = MFMA16(pf, vf, acc_o[nn], 0, 0, 0);
      }
    }
    __syncthreads();
  }

  // row sums -> inv_s (reduce across the 16-lane group)
  float inv_s[4];
#pragma unroll
  for (int r = 0; r < 4; ++r) {
    float s = s_acc[r];
    for (int d = 1; d < 16; d <<= 1) s += __shfl_xor(s, d);
    inv_s[r] = 1.f / s;
  }

  // O epilogue (normalized)
  const int b = bh >> 3, h = bh & 7;
#pragma unroll
  for (int nn = 0; nn < 4; ++nn)
#pragma unroll
    for (int r = 0; r < 4; ++r) {
      int qw = 4 * (lane >> 4) + r;
      int ig = i0 + wvx * 16 + qw;
      int col = h * 64 + nn * 16 + (lane & 15);
      oh[(size_t)(b * 2048 + ig) * 512 + col] = (bf16)(acc_o[nn][r] * inv_s[r]);
    }

  // ---- streaming tail: rescale own rows, zero-fill masked region ----
  asm volatile("s_waitcnt vmcnt(0)" ::: "memory");  // own stores visible via L2
  const int ncols = (qt + 1) * BKt;
  const int jlane = (lane & 15) * 4;
  for (int j = jlane; j < ncols; j += 64) {
#pragma unroll
    for (int r = 0; r < 4; ++r) {
      float* p = attn_b + (size_t)(i0 + wvx * 16 + 4 * (lane >> 4) + r) * Lq + j;
      float4 x = *(float4*)p;
      x.x *= inv_s[r]; x.y *= inv_s[r]; x.z *= inv_s[r]; x.w *= inv_s[r];
      *(float4*)p = x;
    }
  }
  for (int j = ncols + jlane; j < Lq; j += 64) {
#pragma unroll
    for (int r = 0; r < 4; ++r) {
      float* p = attn_b + (size_t)(i0 + wvx * 16 + 4 * (lane >> 4) + r) * Lq + j;
      *(float4*)p = make_float4(0.f, 0.f, 0.f, 0.f);
    }
  }
}

// ---------------------------------------------------------------------------
extern "C" void kernel_launch(void* const* d_in, const int* in_sizes, int n_in,
                              void* d_out, int out_size, void* d_ws, size_t ws_size,
                              hipStream_t stream) {
  const float* q    = (const float*)d_in[0];
  const float* k    = (const float*)d_in[1];
  const float* v    = (const float*)d_in[2];
  const float* wq   = (const float*)d_in[3];
  const float* wq_b = (const float*)d_in[4];
  const float* wk   = (const float*)d_in[5];
  const float* wk_b = (const float*)d_in[6];
  const float* wv   = (const float*)d_in[7];
  const float* wv_b = (const float*)d_in[8];
  const float* fc   = (const float*)d_in[9];
  const float* fc_b = (const float*)d_in[10];
  const float* E    = (const float*)d_in[11];

  if (ws_size < 31719424) return;  // workspace layout below needs ~30.3 MiB
  char* ws = (char*)d_ws;
  bf16* q_bf  = (bf16*)(ws);
  bf16* k_bf  = (bf16*)(ws + 4194304);
  bf16* v_bf  = (bf16*)(ws + 8388608);
  bf16* wq_bf = (bf16*)(ws + 12582912);
  bf16* wk_bf = (bf16*)(ws + 13107200);
  bf16* wv_bf = (bf16*)(ws + 13631488);
  bf16* fc_bf = (bf16*)(ws + 14155776);
  bf16* E_bf  = (bf16*)(ws + 14680064);
  bf16* qh_bf = (bf16*)(ws + 14942208);
  bf16* kh_bf = (bf16*)(ws + 19136512);
  bf16* vt_bf = (bf16*)(ws + 23330816);
  bf16* oh_bf = (bf16*)(ws + 27525120);

  float* out_f  = (float*)d_out;
  float* attn_f = out_f + 2097152;

  convert_all<<<7296, 256, 0, stream>>>(q, k, v, wq, wk, wv, fc, E,
      q_bf, k_bf, v_bf, wq_bf, wk_bf, wv_bf, fc_bf, E_bf);
  gemm512<0><<<dim3(32, 4), 256, 0, stream>>>(q_bf, wq_bf, wq_b, qh_bf);
  gemm512<0><<<dim3(32, 4), 256, 0, stream>>>(k_bf, wk_bf, wk_b, kh_bf);
  gemm512<2><<<dim3(4, 32), 256, 0, stream>>>(wv_bf, v_bf, wv_b, vt_bf);
  attn_kernel<<<512, 256, 0, stream>>>(qh_bf, kh_bf, vt_bf, E_bf, attn_f, oh_bf);
  gemm512<3><<<dim3(32, 4), 256, 0, stream>>>(oh_bf, fc_bf, fc_b, out_f);
}

// Round 5
// 213.007 us; speedup vs baseline: 2.3471x; 1.0426x over previous
//
#include <hip/hip_runtime.h>
#include <hip/hip_bf16.h>
#include <cstdint>

typedef __bf16 bf16;
typedef __attribute__((ext_vector_type(8))) __bf16 bf16x8;
typedef __attribute__((ext_vector_type(4))) __bf16 bf16x4;
typedef __attribute__((ext_vector_type(4))) float f32x4;

#define MFMA16 __builtin_amdgcn_mfma_f32_16x16x32_bf16
#define MASKV (-1e30f)

static constexpr int Lq  = 2048;
static constexpr int BQ  = 64;    // q rows per workgroup (16 per wave)
static constexpr int BKt = 64;    // keys per tile
static constexpr int TW  = 84;    // T strip stride (bf16): 79 used; 42-dword rows

__device__ __forceinline__ void async_load16(const void* g, void* l) {
  __builtin_amdgcn_global_load_lds(
      (__attribute__((address_space(1))) void*)g,
      (__attribute__((address_space(3))) void*)l, 16, 0, 0);
}

// ---------------------------------------------------------------------------
// fp32 -> bf16 conversion of all inputs
// ---------------------------------------------------------------------------
__global__ void convert_all(const float* __restrict__ q, const float* __restrict__ k,
                            const float* __restrict__ v, const float* __restrict__ wq,
                            const float* __restrict__ wk, const float* __restrict__ wv,
                            const float* __restrict__ fc, const float* __restrict__ E,
                            bf16* q_bf, bf16* k_bf, bf16* v_bf, bf16* wq_bf,
                            bf16* wk_bf, bf16* wv_bf, bf16* fc_bf, bf16* E_bf)
{
  int i = blockIdx.x * blockDim.x + threadIdx.x;   // vec4 index
  const float* src; bf16* dst; int rel;
  if      (i < 524288)  { src = q;  dst = q_bf;  rel = i; }
  else if (i < 1048576) { src = k;  dst = k_bf;  rel = i - 524288; }
  else if (i < 1572864) { src = v;  dst = v_bf;  rel = i - 1048576; }
  else if (i < 1638400) { src = wq; dst = wq_bf; rel = i - 1572864; }
  else if (i < 1703936) { src = wk; dst = wk_bf; rel = i - 1638400; }
  else if (i < 1769472) { src = wv; dst = wv_bf; rel = i - 1703936; }
  else if (i < 1835008) { src = fc; dst = fc_bf; rel = i - 1769472; }
  else if (i < 1867776) { src = E;  dst = E_bf;  rel = i - 1835008; }
  else return;
  float4 x = *(const float4*)(src + (size_t)rel * 4);
  bf16x4 o;
  o[0] = (bf16)x.x; o[1] = (bf16)x.y; o[2] = (bf16)x.z; o[3] = (bf16)x.w;
  *(bf16x4*)(dst + (size_t)rel * 4) = o;
}

__global__ void zero_s(float* __restrict__ s_buf) {
  int i = blockIdx.x * blockDim.x + threadIdx.x;   // float4 index, 8192 total
  if (i < 8192) ((float4*)s_buf)[i] = make_float4(0.f, 0.f, 0.f, 0.f);
}

__global__ void combine_o(const bf16* __restrict__ O0, const bf16* __restrict__ O1,
                          bf16* __restrict__ oh) {
  int i = blockIdx.x * blockDim.x + threadIdx.x;   // x8 index, 262144 total
  if (i >= 262144) return;
  bf16x8 a = *(const bf16x8*)(O0 + (size_t)i * 8);
  bf16x8 b = *(const bf16x8*)(O1 + (size_t)i * 8);
  bf16x8 o;
#pragma unroll
  for (int j = 0; j < 8; ++j) o[j] = (bf16)((float)a[j] + (float)b[j]);
  *(bf16x8*)(oh + (size_t)i * 8) = o;
}

// ---------------------------------------------------------------------------
// Generic 128x128-tile bf16 GEMM, C[i][j] = sum_k A[i][k]*B[j][k] + bias
// MODE 0: C bf16 (B,H,L,DH) ; MODE 2: C bf16 (B,H,DH,L), bias[i] ; MODE 3: fp32
// ---------------------------------------------------------------------------
template<int MODE>
__global__ __launch_bounds__(256, 2)
void gemm512(const bf16* __restrict__ A, const bf16* __restrict__ Bm,
             const float* __restrict__ bias, void* __restrict__ Cv)
{
  __shared__ __align__(16) char lA[16384];
  __shared__ __align__(16) char lB[16384];
  const int tid = threadIdx.x, lane = tid & 63, wv = tid >> 6;
  const int wr = wv >> 1, wc = wv & 1;
  const int tm = blockIdx.x, tn = blockIdx.y;

  f32x4 acc[4][4];
#pragma unroll
  for (int m = 0; m < 4; ++m)
#pragma unroll
    for (int n = 0; n < 4; ++n) acc[m][n] = (f32x4){0.f, 0.f, 0.f, 0.f};

  for (int k0 = 0; k0 < 512; k0 += 64) {
    __syncthreads();
#pragma unroll
    for (int it = 0; it < 4; ++it) {
      int slot = it * 256 + wv * 64 + lane;
      int row = slot >> 3, c = slot & 7;
      int gk = k0 + ((c ^ (row & 7)) * 8);
      async_load16(A  + (size_t)(tm * 128 + row) * 512 + gk, lA + (it * 256 + wv * 64) * 16);
      async_load16(Bm + (size_t)(tn * 128 + row) * 512 + gk, lB + (it * 256 + wv * 64) * 16);
    }
    __syncthreads();
#pragma unroll
    for (int kc = 0; kc < 2; ++kc) {
      bf16x8 af[4], bfr[4];
#pragma unroll
      for (int m = 0; m < 4; ++m) {
        int row = wr * 64 + m * 16 + (lane & 15);
        int ch = ((lane >> 4) + kc * 4) ^ (row & 7);
        af[m] = *(const bf16x8*)(lA + row * 128 + ch * 16);
      }
#pragma unroll
      for (int n = 0; n < 4; ++n) {
        int row = wc * 64 + n * 16 + (lane & 15);
        int ch = ((lane >> 4) + kc * 4) ^ (row & 7);
        bfr[n] = *(const bf16x8*)(lB + row * 128 + ch * 16);
      }
#pragma unroll
      for (int m = 0; m < 4; ++m)
#pragma unroll
        for (int n = 0; n < 4; ++n)
          acc[m][n] = MFMA16(af[m], bfr[n], acc[m][n], 0, 0, 0);
    }
  }

#pragma unroll
  for (int m = 0; m < 4; ++m)
#pragma unroll
    for (int n = 0; n < 4; ++n)
#pragma unroll
      for (int r = 0; r < 4; ++r) {
        int gi = tm * 128 + wr * 64 + m * 16 + 4 * (lane >> 4) + r;
        int gj = tn * 128 + wc * 64 + n * 16 + (lane & 15);
        float vv = acc[m][n][r] + ((MODE == 2) ? bias[gi] : bias[gj]);
        if (MODE == 3) {
          ((float*)Cv)[(size_t)gi * 512 + gj] = vv;
        } else if (MODE == 2) {
          int h = gi >> 6, dh = gi & 63, b = gj >> 11, l = gj & 2047;
          ((bf16*)Cv)[((size_t)((b * 8 + h) * 64 + dh)) * 2048 + l] = (bf16)vv;
        } else {
          int b = gi >> 11, l = gi & 2047, h = gj >> 6, dh = gj & 63;
          ((bf16*)Cv)[((size_t)((b * 8 + h) * 2048 + l)) * 64 + dh] = (bf16)vv;
        }
      }
}

// ---------------------------------------------------------------------------
// Attention helpers
// ---------------------------------------------------------------------------
__device__ __forceinline__ void stage_k(const bf16* __restrict__ kb, int j0,
                                        char* dst, int tid) {
#pragma unroll
  for (int it = 0; it < 2; ++it) {
    int slot = it * 256 + tid;
    int row = slot >> 3, c = slot & 7;
    async_load16(kb + (size_t)(j0 + row) * 64 + ((c ^ (row & 7)) * 8), dst + slot * 16);
  }
}
__device__ __forceinline__ void stage_v(const bf16* __restrict__ vb, int j0,
                                        char* dst, int tid) {
#pragma unroll
  for (int it = 0; it < 2; ++it) {
    int slot = it * 256 + tid;
    int row = slot >> 3, c = slot & 7;
    async_load16(vb + (size_t)row * Lq + j0 + ((c ^ (row & 7)) * 8), dst + slot * 16);
  }
}

// Logits for one 16q x 64k tile: acc_s = (QK + Srel)/8, masked entries = MASKV.
__device__ __forceinline__ void attn_logits3(
    int i0, int j0, int wvx, int lane,
    const bf16x8 qf0, const bf16x8 qf1,
    const bf16* __restrict__ Ebf, const char* lk, bf16* tst, f32x4 acc_s[4])
{
  const int rbase = i0 + wvx * 16 - j0 - 63;
  f32x4 acc_t[5];
#pragma unroll
  for (int cf = 0; cf < 5; ++cf) {
    int r = rbase + cf * 16 + (lane & 15);
    int re = 2047 - r; re = re < 0 ? 0 : (re > 2047 ? 2047 : re);
    const bf16* ep = Ebf + (size_t)re * 64 + (lane >> 4) * 8;
    f32x4 a = (f32x4){0.f, 0.f, 0.f, 0.f};
    a = MFMA16(qf0, *(const bf16x8*)ep, a, 0, 0, 0);
    a = MFMA16(qf1, *(const bf16x8*)(ep + 32), a, 0, 0, 0);
    acc_t[cf] = a;
  }
#pragma unroll
  for (int cf = 0; cf < 4; ++cf) {
    int key = cf * 16 + (lane & 15);
    int c0 = (lane >> 4) ^ (key & 7);
    int c1 = ((lane >> 4) + 4) ^ (key & 7);
    f32x4 a = (f32x4){0.f, 0.f, 0.f, 0.f};
    a = MFMA16(qf0, *(const bf16x8*)(lk + key * 128 + c0 * 16), a, 0, 0, 0);
    a = MFMA16(qf1, *(const bf16x8*)(lk + key * 128 + c1 * 16), a, 0, 0, 0);
    acc_s[cf] = a;
  }
#pragma unroll
  for (int cf = 0; cf < 5; ++cf)
#pragma unroll
    for (int r = 0; r < 4; ++r)
      tst[(4 * (lane >> 4) + r) * TW + cf * 16 + (lane & 15)] = (bf16)acc_t[cf][r];
  asm volatile("s_waitcnt lgkmcnt(0)" ::: "memory");
  __builtin_amdgcn_sched_barrier(0);
#pragma unroll
  for (int cf = 0; cf < 4; ++cf) {
    int kl = cf * 16 + (lane & 15);
#pragma unroll
    for (int r = 0; r < 4; ++r) {
      int qw = 4 * (lane >> 4) + r;
      float t = (float)tst[qw * TW + (qw - kl + 63)];
      float vv = (acc_s[cf][r] + t) * 0.125f;
      if (j0 + kl > i0 + wvx * 16 + qw) vv = MASKV;
      acc_s[cf][r] = vv;
    }
  }
}

// ---------------------------------------------------------------------------
// PASS 1: row sums of exp(logits) via atomicAdd into s_buf[bh*2048 + row].
// Grid: 16 bh * 144 j-chunk-blocks (4 tiles each).
// ---------------------------------------------------------------------------
__global__ __launch_bounds__(256, 4)
void pass1_sums(const bf16* __restrict__ qh, const bf16* __restrict__ kh,
                const bf16* __restrict__ Ebf, float* __restrict__ s_buf)
{
  __shared__ __align__(16) char lds_k[2][64 * 128];
  __shared__ __align__(16) char lds_t[4][16 * TW * 2];
  const int tid = threadIdx.x, lane = tid & 63, wvx = tid >> 6;
  const int bid = blockIdx.x;
  const int bh  = bid / 144;
  int f = bid - bh * 144, qt = 0;
#pragma unroll 1
  for (int q = 0; q < 32; ++q) {
    int c = (q + 4) >> 2;
    if (f < c) { qt = q; break; }
    f -= c;
  }
  const int jbeg = f * 4;
  const int jend = (jbeg + 4 < qt + 1) ? jbeg + 4 : qt + 1;
  const int i0 = qt * BQ;

  const bf16* qb = qh + (size_t)bh * Lq * 64;
  const bf16* kb = kh + (size_t)bh * Lq * 64;
  bf16* tst = (bf16*)lds_t[wvx];

  const int qrow = i0 + wvx * 16 + (lane & 15);
  const bf16x8 qf0 = *(const bf16x8*)(qb + (size_t)qrow * 64 + (lane >> 4) * 8);
  const bf16x8 qf1 = *(const bf16x8*)(qb + (size_t)qrow * 64 + 32 + (lane >> 4) * 8);

  f32x4 acc_s[4];
  float s_acc[4] = {0.f, 0.f, 0.f, 0.f};

  stage_k(kb, jbeg * BKt, lds_k[0], tid);
  __syncthreads();
  for (int jt = jbeg; jt < jend; ++jt) {
    const int lt = (jt - jbeg) & 1;
    if (jt + 1 < jend) stage_k(kb, (jt + 1) * BKt, lds_k[lt ^ 1], tid);
    attn_logits3(i0, jt * BKt, wvx, lane, qf0, qf1, Ebf, lds_k[lt], tst, acc_s);
#pragma unroll
    for (int r = 0; r < 4; ++r) {
#pragma unroll
      for (int cf = 0; cf < 4; ++cf) s_acc[r] += __expf(acc_s[cf][r]);
    }
    __syncthreads();
  }
#pragma unroll
  for (int r = 0; r < 4; ++r) {
    float s = s_acc[r];
    for (int d = 1; d < 16; d <<= 1) s += __shfl_xor(s, d);
    if ((lane & 15) == 0)
      atomicAdd(&s_buf[bh * Lq + i0 + wvx * 16 + 4 * (lane >> 4) + r], s);
  }
}

// ---------------------------------------------------------------------------
// MAIN: normalized attn write + O partials. Grid (512, 2): x as before
// (complementary qt pairing, bh per XCD), y = j-half. jh==1 also zero-fills
// the masked upper region. O partial (normalized) -> O0/O1 (bf16, oh layout).
// ---------------------------------------------------------------------------
__global__ __launch_bounds__(256, 3)
void attn_main(const bf16* __restrict__ qh, const bf16* __restrict__ kh,
               const bf16* __restrict__ vt, const bf16* __restrict__ Ebf,
               const float* __restrict__ s_buf, float* __restrict__ attn_out,
               bf16* __restrict__ O0, bf16* __restrict__ O1)
{
  __shared__ __align__(16) char lds_k[2][64 * 128];
  __shared__ __align__(16) char lds_v[2][64 * 128];
  __shared__ __align__(16) char lds_t[4][16 * TW * 2];

  const int tid = threadIdx.x, lane = tid & 63, wvx = tid >> 6;
  const int x    = blockIdx.x, jh = blockIdx.y;
  const int half = x >> 8;
  const int r0   = x & 255;
  const int xcd  = r0 & 7;
  const int idx  = r0 >> 3;
  const int bh   = 2 * xcd + half;
  const int qt   = half ? idx : 31 - idx;
  const int i0   = qt * BQ;
  const int njt  = qt + 1;
  const int nj0  = (njt + 1) >> 1;
  const int jbeg = jh ? nj0 : 0;
  const int jend = jh ? njt : nj0;
  bf16* Opart = jh ? O1 : O0;

  const bf16* qb = qh + (size_t)bh * Lq * 64;
  const bf16* kb = kh + (size_t)bh * Lq * 64;
  const bf16* vb = vt + (size_t)bh * 64 * Lq;
  float* attn_b = attn_out + (size_t)bh * Lq * Lq;
  bf16* tst = (bf16*)lds_t[wvx];
  bf16* pst = tst;                       // P strip alias (16 x 64, swizzled)

  const int qrow = i0 + wvx * 16 + (lane & 15);
  const bf16x8 qf0 = *(const bf16x8*)(qb + (size_t)qrow * 64 + (lane >> 4) * 8);
  const bf16x8 qf1 = *(const bf16x8*)(qb + (size_t)qrow * 64 + 32 + (lane >> 4) * 8);

  float inv_s[4];
#pragma unroll
  for (int r = 0; r < 4; ++r)
    inv_s[r] = 1.f / s_buf[bh * Lq + i0 + wvx * 16 + 4 * (lane >> 4) + r];

  f32x4 acc_s[4];
  f32x4 acc_o[4];
#pragma unroll
  for (int nn = 0; nn < 4; ++nn) acc_o[nn] = (f32x4){0.f, 0.f, 0.f, 0.f};

  if (jbeg < jend) {
    stage_k(kb, jbeg * BKt, lds_k[0], tid);
    stage_v(vb, jbeg * BKt, lds_v[0], tid);
    __syncthreads();
    for (int jt = jbeg; jt < jend; ++jt) {
      const int j0 = jt * BKt;
      const int lt = (jt - jbeg) & 1;
      if (jt + 1 < jend) {
        stage_k(kb, j0 + BKt, lds_k[lt ^ 1], tid);
        stage_v(vb, j0 + BKt, lds_v[lt ^ 1], tid);
      }
      attn_logits3(i0, j0, wvx, lane, qf0, qf1, Ebf, lds_k[lt], tst, acc_s);
      asm volatile("" ::: "memory");   // order P writes after T gathers
      // normalized exp -> swizzled P strip (bf16)
#pragma unroll
      for (int cf = 0; cf < 4; ++cf) {
        int kl = cf * 16 + (lane & 15);
        int chs = kl >> 3;
#pragma unroll
        for (int r = 0; r < 4; ++r) {
          int qw = 4 * (lane >> 4) + r;
          float p = __expf(acc_s[cf][r]) * inv_s[r];
          pst[qw * 64 + ((chs ^ (qw & 7)) * 8) + (kl & 7)] = (bf16)p;
        }
      }
      asm volatile("s_waitcnt lgkmcnt(0)" ::: "memory");
      __builtin_amdgcn_sched_barrier(0);
      // attn write: 256B-contiguous per 8-lane group
#pragma unroll
      for (int it = 0; it < 2; ++it) {
        int qw = it * 8 + (lane >> 3);
        int c = lane & 7;
        bf16x8 pv = *(const bf16x8*)(pst + qw * 64 + ((c ^ (qw & 7)) * 8));
        float* dst = attn_b + (size_t)(i0 + wvx * 16 + qw) * Lq + j0 + c * 8;
        float4 f0, f1;
        f0.x = (float)pv[0]; f0.y = (float)pv[1]; f0.z = (float)pv[2]; f0.w = (float)pv[3];
        f1.x = (float)pv[4]; f1.y = (float)pv[5]; f1.z = (float)pv[6]; f1.w = (float)pv[7];
        *(float4*)dst = f0; *(float4*)(dst + 4) = f1;
      }
      // O += P.V (normalized)
#pragma unroll
      for (int kc = 0; kc < 2; ++kc) {
        int qa = lane & 15;
        int cha = (kc * 4 + (lane >> 4)) ^ (qa & 7);
        bf16x8 pf = *(const bf16x8*)(pst + qa * 64 + cha * 8);
#pragma unroll
        for (int nn = 0; nn < 4; ++nn) {
          int dh = nn * 16 + (lane & 15);
          int chv = (kc * 4 + (lane >> 4)) ^ (dh & 7);
          bf16x8 vf = *(const bf16x8*)(lds_v[lt] + dh * 128 + chv * 16);
          acc_o[nn] = MFMA16(pf, vf, acc_o[nn], 0, 0, 0);
        }
      }
      __syncthreads();
    }
  }

  // O partial write (always, even when empty -> zeros; buffers are poisoned)
  const int b = bh >> 3, h = bh & 7;
#pragma unroll
  for (int nn = 0; nn < 4; ++nn)
#pragma unroll
    for (int r = 0; r < 4; ++r) {
      int qw = 4 * (lane >> 4) + r;
      int ig = i0 + wvx * 16 + qw;
      int col = h * 64 + nn * 16 + (lane & 15);
      Opart[(size_t)(b * 2048 + ig) * 512 + col] = (bf16)acc_o[nn][r];
    }

  // zero-fill masked upper region (jh==1 blocks only)
  if (jh == 1) {
    const int jlane = (lane & 15) * 4;
    for (int j = njt * BKt + jlane; j < Lq; j += 64) {
#pragma unroll
      for (int r = 0; r < 4; ++r) {
        float* p = attn_b + (size_t)(i0 + wvx * 16 + 4 * (lane >> 4) + r) * Lq + j;
        *(float4*)p = make_float4(0.f, 0.f, 0.f, 0.f);
      }
    }
  }
}

// ---------------------------------------------------------------------------
extern "C" void kernel_launch(void* const* d_in, const int* in_sizes, int n_in,
                              void* d_out, int out_size, void* d_ws, size_t ws_size,
                              hipStream_t stream) {
  const float* q    = (const float*)d_in[0];
  const float* k    = (const float*)d_in[1];
  const float* v    = (const float*)d_in[2];
  const float* wq   = (const float*)d_in[3];
  const float* wq_b = (const float*)d_in[4];
  const float* wk   = (const float*)d_in[5];
  const float* wk_b = (const float*)d_in[6];
  const float* wv   = (const float*)d_in[7];
  const float* wv_b = (const float*)d_in[8];
  const float* fc   = (const float*)d_in[9];
  const float* fc_b = (const float*)d_in[10];
  const float* E    = (const float*)d_in[11];

  if (ws_size < 31719424) return;  // workspace layout below needs ~30.3 MiB
  char* ws = (char*)d_ws;
  bf16* q_bf  = (bf16*)(ws);                 // dead after gemm q  -> reused as O0
  bf16* k_bf  = (bf16*)(ws + 4194304);       // dead after gemm k  -> reused as O1
  bf16* v_bf  = (bf16*)(ws + 8388608);
  bf16* wq_bf = (bf16*)(ws + 12582912);      // dead after gemm q  -> reused as s_buf
  bf16* wk_bf = (bf16*)(ws + 13107200);
  bf16* wv_bf = (bf16*)(ws + 13631488);
  bf16* fc_bf = (bf16*)(ws + 14155776);
  bf16* E_bf  = (bf16*)(ws + 14680064);
  bf16* qh_bf = (bf16*)(ws + 14942208);
  bf16* kh_bf = (bf16*)(ws + 19136512);
  bf16* vt_bf = (bf16*)(ws + 23330816);
  bf16* oh_bf = (bf16*)(ws + 27525120);

  bf16*  O0    = (bf16*)(ws);                // aliases q_bf (4 MiB, exact fit)
  bf16*  O1    = (bf16*)(ws + 4194304);      // aliases k_bf
  float* s_buf = (float*)(ws + 12582912);    // aliases wq_bf (128 KiB used)

  float* out_f  = (float*)d_out;
  float* attn_f = out_f + 2097152;

  convert_all<<<7296, 256, 0, stream>>>(q, k, v, wq, wk, wv, fc, E,
      q_bf, k_bf, v_bf, wq_bf, wk_bf, wv_bf, fc_bf, E_bf);
  gemm512<0><<<dim3(32, 4), 256, 0, stream>>>(q_bf, wq_bf, wq_b, qh_bf);   // uses wq_bf
  zero_s<<<32, 256, 0, stream>>>(s_buf);                                   // then reuse it
  gemm512<0><<<dim3(32, 4), 256, 0, stream>>>(k_bf, wk_bf, wk_b, kh_bf);
  gemm512<2><<<dim3(4, 32), 256, 0, stream>>>(wv_bf, v_bf, wv_b, vt_bf);
  pass1_sums<<<2304, 256, 0, stream>>>(qh_bf, kh_bf, E_bf, s_buf);
  attn_main<<<dim3(512, 2), 256, 0, stream>>>(qh_bf, kh_bf, vt_bf, E_bf,
                                              s_buf, attn_f, O0, O1);
  combine_o<<<1024, 256, 0, stream>>>(O0, O1, oh_bf);
  gemm512<3><<<dim3(32, 4), 256, 0, stream>>>(oh_bf, fc_bf, fc_b, out_f);
}